// Round 12
// baseline (132.379 us; speedup 1.0000x reference)
//
#include <hip/hip_runtime.h>

// GraphFeatureTokenizer via MFMA: B=16, N=2048, E=4096, K=32, D=768, V=1024, T=6144
// out[b,t,d] = emb[data[row][d]] + dot(ie[t,:64], lap_w[d,:64]) + order_emb[i0==i1][d]
//   ie[t] = concat(eig[b,i0], eig[b,i1]);  OUT = IE @ W^T via mfma_f32_16x16x32_bf16.
// A-frag: lane holds 8 contiguous k of token (lane&15) -> straight from eig row.
// B-frag: lane holds 8 contiguous k of d-row (lane&15) -> straight from lap_w row.
// C layout (m89): col = lane&15, row = (lane>>4)*4 + reg.
// Pipeline: s_acc double-buffered, ONE barrier/iter; tokv+eig prefetched 1 iter
// ahead; s_emb gather pre-barrier. XCD-chunked bijective swizzle; d-slice
// fastest-varying. Allocating token loads (L3 retains input); nt stores.
// Occupancy: 4 blocks/CU (VGPR=72 << 128; LDS 38.4KB x 4 = 153.6 <= 160KB) --
// the R4-era (256,3) cap was for w[64] register pressure that no longer exists.

constexpr int CB = 16;
constexpr int CN = 2048;
constexpr int CE = 4096;
constexpr int CT = 6144;
constexpr int CK = 32;
constexpr int CD = 768;
constexpr int CV = 1024;
constexpr int TPB = 256;
constexpr int TOK = 128;           // tokens per block
constexpr int CPG = CT / TOK;      // 48 chunks per graph (0..15 node, 16..47 edge)
constexpr int NSL = 3;             // d-slices per chunk (768/256)
constexpr int NXCD = 8;
constexpr int NBLK = CB * CPG * NSL;      // 2304
constexpr int PER_XCD = NBLK / NXCD;      // 288 (exact)

using f32x4  = __attribute__((ext_vector_type(4))) float;
using i32x4  = __attribute__((ext_vector_type(4))) int;
using bf16x8 = __attribute__((ext_vector_type(8))) short;

__device__ __forceinline__ short f2bf(float f) {
    union { float f; unsigned u; } x{f};
    unsigned r = x.u + 0x7fffu + ((x.u >> 16) & 1u);   // RNE
    return (short)(r >> 16);
}
__device__ __forceinline__ bf16x8 cvt8(f32x4 a, f32x4 b) {
    bf16x8 r;
    r[0] = f2bf(a[0]); r[1] = f2bf(a[1]); r[2] = f2bf(a[2]); r[3] = f2bf(a[3]);
    r[4] = f2bf(b[0]); r[5] = f2bf(b[1]); r[6] = f2bf(b[2]); r[7] = f2bf(b[3]);
    return r;
}

__global__ __launch_bounds__(TPB, 4) void gft_mfma(
    const int* __restrict__ node_data,
    const int* __restrict__ edge_data,
    const int* __restrict__ padded_index,  // [B,T,2]
    const float* __restrict__ eig,         // [B*N, K]
    const float* __restrict__ emb,         // [V]
    const float* __restrict__ lap_w,       // [D, 2K]
    const float* __restrict__ order_emb,   // [2, D]
    float* __restrict__ out)               // [B, T, D]
{
    __shared__ float s_emb[CV];
    __shared__ int2 s_pi[TOK];
    __shared__ __align__(16) float s_acc[2][16][260];  // dbuf; 1040B row stride

    const int tid  = threadIdx.x;
    const int lane = tid & 63;
    const int wid  = tid >> 6;
    // XCD-chunked bijective swizzle: hw round-robins bid%8 across XCDs, so
    // logical id L = (bid%8)*288 + bid/8 gives each XCD a contiguous range.
    const int L = (blockIdx.x % NXCD) * PER_XCD + blockIdx.x / NXCD;
    const int slice = L % NSL;                   // d-slice fastest-varying
    const int cg    = L / NSL;                   // global chunk id
    const int b = cg / CPG, c = cg % CPG;
    const int dbase = slice * 256;
    const int dloc  = dbase + wid * 64;    // wave's 64-wide d slice (MFMA phase)
    const int dq    = dbase + 4 * lane;    // lane's 4-wide d slice (epilogue phase)

    for (int i = tid; i < CV; i += TPB) s_emb[i] = emb[i];
    {
        const int2* pi = (const int2*)padded_index + (size_t)(b * CT + c * TOK);
        if (tid < TOK) s_pi[tid] = pi[tid];
    }

    const int* __restrict__ dptr = (c * TOK < CN)
        ? node_data + ((size_t)b * CN + c * TOK) * CD
        : edge_data + ((size_t)b * CE + (c * TOK - CN)) * CD;
    const float* __restrict__ eig_b = eig + (size_t)b * CN * CK;
    float* __restrict__ outp = out + ((size_t)(b * CT + c * TOK)) * CD;

    const int koff = (lane >> 4) * 8;   // k sub-block for both A and B frags
    const int dl   = lane & 15;

    // ---- B fragments: 4 d-tiles x 2 K-halves, straight from lap_w rows ----
    bf16x8 bw[4][2];
#pragma unroll
    for (int n = 0; n < 4; ++n) {
        const float* wr = lap_w + (size_t)(dloc + 16 * n + dl) * (2 * CK) + koff;
        bw[n][0] = cvt8(*(const f32x4*)wr,        *(const f32x4*)(wr + 4));
        bw[n][1] = cvt8(*(const f32x4*)(wr + 32), *(const f32x4*)(wr + 36));
    }
    const f32x4 oe0q = *(const f32x4*)(order_emb + dq);
    const f32x4 oe1q = *(const f32x4*)(order_emb + CD + dq);
    __syncthreads();   // s_emb / s_pi ready (once)

    // ---- iter-0 prefetch: eig rows + token rows ----
    f32x4 q00, q01, q10, q11;
    {
        const int2 ia = s_pi[dl];
        const float* e0 = eig_b + (size_t)ia.x * CK + koff;
        const float* e1 = eig_b + (size_t)ia.y * CK + koff;
        q00 = *(const f32x4*)e0; q01 = *(const f32x4*)(e0 + 4);
        q10 = *(const f32x4*)e1; q11 = *(const f32x4*)(e1 + 4);
    }
    i32x4 tokc[4];
#pragma unroll
    for (int s = 0; s < 4; ++s)
        tokc[s] = *(const i32x4*)(dptr + (size_t)(4 * s + wid) * CD + dq);

    for (int it = 0; it < TOK / 16; ++it) {
        const int t0 = it * 16;

        // s_emb gather for THIS iter's tokens (pre-barrier; overlaps MFMA)
        float embv[4][4];
#pragma unroll
        for (int s = 0; s < 4; ++s)
#pragma unroll
            for (int j = 0; j < 4; ++j)
                embv[s][j] = s_emb[tokc[s][j]];

        const bf16x8 a0 = cvt8(q00, q01);
        const bf16x8 a1 = cvt8(q10, q11);

        // prefetch NEXT iter's eig + token rows (allocating loads: L3 retains)
        i32x4 tokn[4];
        if (it + 1 < TOK / 16) {
            const int2 ia = s_pi[t0 + 16 + dl];
            const float* e0 = eig_b + (size_t)ia.x * CK + koff;
            const float* e1 = eig_b + (size_t)ia.y * CK + koff;
            q00 = *(const f32x4*)e0; q01 = *(const f32x4*)(e0 + 4);
            q10 = *(const f32x4*)e1; q11 = *(const f32x4*)(e1 + 4);
#pragma unroll
            for (int s = 0; s < 4; ++s)
                tokn[s] = *(const i32x4*)(dptr + (size_t)(t0 + 16 + 4 * s + wid) * CD + dq);
        }

        f32x4 acc[4];
#pragma unroll
        for (int n = 0; n < 4; ++n) {
            f32x4 z = {0.f, 0.f, 0.f, 0.f};
            z = __builtin_amdgcn_mfma_f32_16x16x32_bf16(a0, bw[n][0], z, 0, 0, 0);
            acc[n] = __builtin_amdgcn_mfma_f32_16x16x32_bf16(a1, bw[n][1], z, 0, 0, 0);
        }

        // transpose through LDS buf it&1 (iter it+2 writes can't pass barrier it+1)
#pragma unroll
        for (int n = 0; n < 4; ++n)
#pragma unroll
            for (int r = 0; r < 4; ++r)
                s_acc[it & 1][(lane >> 4) * 4 + r][wid * 64 + 16 * n + dl] = acc[n][r];
        asm volatile("s_waitcnt lgkmcnt(0)" ::: "memory");
        __builtin_amdgcn_s_barrier();

        // ---- minimal post-barrier epilogue: wave owns 4 rows, lane owns 4 d ----
#pragma unroll
        for (int s = 0; s < 4; ++s) {
            const int tr = 4 * s + wid;
            const int2 i01 = s_pi[t0 + tr];
            const f32x4 av = *(const f32x4*)&s_acc[it & 1][tr][4 * lane];
            const f32x4 oe = (i01.x == i01.y) ? oe1q : oe0q;
            f32x4 y;
            y[0] = av[0] + embv[s][0] + oe[0];
            y[1] = av[1] + embv[s][1] + oe[1];
            y[2] = av[2] + embv[s][2] + oe[2];
            y[3] = av[3] + embv[s][3] + oe[3];
            __builtin_nontemporal_store(
                y, (f32x4*)(outp + (size_t)(t0 + tr) * CD + dq));
        }

#pragma unroll
        for (int s = 0; s < 4; ++s) tokc[s] = tokn[s];
    }
}

extern "C" void kernel_launch(void* const* d_in, const int* in_sizes, int n_in,
                              void* d_out, int out_size, void* d_ws, size_t ws_size,
                              hipStream_t stream) {
    // inputs: 0 edge_index, 1 edge_data, 2 node_data, 3 node_num, 4 edge_num,
    // 5 padded_index, 6 padding_mask, 7 padded_node_mask, 8 padded_edge_mask,
    // 9 lap_eigvec, 10 emb_table, 11 lap_w, 12 order_emb
    const int*   edge_data    = (const int*)d_in[1];
    const int*   node_data    = (const int*)d_in[2];
    const int*   padded_index = (const int*)d_in[5];
    const float* lap_eigvec   = (const float*)d_in[9];
    const float* emb_table    = (const float*)d_in[10];
    const float* lap_w        = (const float*)d_in[11];
    const float* order_emb    = (const float*)d_in[12];
    float* out = (float*)d_out;

    dim3 grid(NBLK);  // 2304
    gft_mfma<<<grid, TPB, 0, stream>>>(node_data, edge_data, padded_index,
                                       lap_eigvec, emb_table, lap_w, order_emb, out);
}

// Round 13
// 122.949 us; speedup vs baseline: 1.0767x; 1.0767x over previous
//
#include <hip/hip_runtime.h>

// GraphFeatureTokenizer via MFMA: B=16, N=2048, E=4096, K=32, D=768, V=1024, T=6144
// out[b,t,d] = emb[data[row][d]] + dot(ie[t,:64], lap_w[d,:64]) + order_emb[i0==i1][d]
//   ie[t] = concat(eig[b,i0], eig[b,i1]);  OUT = IE @ W^T via mfma_f32_16x16x32_bf16.
// A-frag: lane holds 8 contiguous k of token (lane&15) -> straight from eig row.
// B-frag: lane holds 8 contiguous k of d-row (lane&15) -> straight from lap_w row.
// C layout (m89): col = lane&15, row = (lane>>4)*4 + reg.
// Pipeline: s_acc double-buffered, ONE barrier/iter; tokv+eig prefetched 1 iter
// ahead; s_emb gather pre-barrier. XCD-chunked bijective swizzle; d-slice
// fastest-varying. Allocating token loads (L3 retains input); nt stores.
// Occupancy: 3 blocks/CU ON PURPOSE — R12 measured 4 blocks/CU: dur 123->132us,
// FETCH 154->166MB, WRITE 295->318MB. Extra co-resident streams degrade the
// L2/DRAM locality this schedule depends on. Do not raise to 4.

constexpr int CB = 16;
constexpr int CN = 2048;
constexpr int CE = 4096;
constexpr int CT = 6144;
constexpr int CK = 32;
constexpr int CD = 768;
constexpr int CV = 1024;
constexpr int TPB = 256;
constexpr int TOK = 128;           // tokens per block
constexpr int CPG = CT / TOK;      // 48 chunks per graph (0..15 node, 16..47 edge)
constexpr int NSL = 3;             // d-slices per chunk (768/256)
constexpr int NXCD = 8;
constexpr int NBLK = CB * CPG * NSL;      // 2304
constexpr int PER_XCD = NBLK / NXCD;      // 288 (exact)

using f32x4  = __attribute__((ext_vector_type(4))) float;
using i32x4  = __attribute__((ext_vector_type(4))) int;
using bf16x8 = __attribute__((ext_vector_type(8))) short;

__device__ __forceinline__ short f2bf(float f) {
    union { float f; unsigned u; } x{f};
    unsigned r = x.u + 0x7fffu + ((x.u >> 16) & 1u);   // RNE
    return (short)(r >> 16);
}
__device__ __forceinline__ bf16x8 cvt8(f32x4 a, f32x4 b) {
    bf16x8 r;
    r[0] = f2bf(a[0]); r[1] = f2bf(a[1]); r[2] = f2bf(a[2]); r[3] = f2bf(a[3]);
    r[4] = f2bf(b[0]); r[5] = f2bf(b[1]); r[6] = f2bf(b[2]); r[7] = f2bf(b[3]);
    return r;
}

__global__ __launch_bounds__(TPB, 3) void gft_mfma(
    const int* __restrict__ node_data,
    const int* __restrict__ edge_data,
    const int* __restrict__ padded_index,  // [B,T,2]
    const float* __restrict__ eig,         // [B*N, K]
    const float* __restrict__ emb,         // [V]
    const float* __restrict__ lap_w,       // [D, 2K]
    const float* __restrict__ order_emb,   // [2, D]
    float* __restrict__ out)               // [B, T, D]
{
    __shared__ float s_emb[CV];
    __shared__ int2 s_pi[TOK];
    __shared__ __align__(16) float s_acc[2][16][260];  // dbuf; 1040B row stride

    const int tid  = threadIdx.x;
    const int lane = tid & 63;
    const int wid  = tid >> 6;
    // XCD-chunked bijective swizzle: hw round-robins bid%8 across XCDs, so
    // logical id L = (bid%8)*288 + bid/8 gives each XCD a contiguous range.
    const int L = (blockIdx.x % NXCD) * PER_XCD + blockIdx.x / NXCD;
    const int slice = L % NSL;                   // d-slice fastest-varying
    const int cg    = L / NSL;                   // global chunk id
    const int b = cg / CPG, c = cg % CPG;
    const int dbase = slice * 256;
    const int dloc  = dbase + wid * 64;    // wave's 64-wide d slice (MFMA phase)
    const int dq    = dbase + 4 * lane;    // lane's 4-wide d slice (epilogue phase)

    for (int i = tid; i < CV; i += TPB) s_emb[i] = emb[i];
    {
        const int2* pi = (const int2*)padded_index + (size_t)(b * CT + c * TOK);
        if (tid < TOK) s_pi[tid] = pi[tid];
    }

    const int* __restrict__ dptr = (c * TOK < CN)
        ? node_data + ((size_t)b * CN + c * TOK) * CD
        : edge_data + ((size_t)b * CE + (c * TOK - CN)) * CD;
    const float* __restrict__ eig_b = eig + (size_t)b * CN * CK;
    float* __restrict__ outp = out + ((size_t)(b * CT + c * TOK)) * CD;

    const int koff = (lane >> 4) * 8;   // k sub-block for both A and B frags
    const int dl   = lane & 15;

    // ---- B fragments: 4 d-tiles x 2 K-halves, straight from lap_w rows ----
    bf16x8 bw[4][2];
#pragma unroll
    for (int n = 0; n < 4; ++n) {
        const float* wr = lap_w + (size_t)(dloc + 16 * n + dl) * (2 * CK) + koff;
        bw[n][0] = cvt8(*(const f32x4*)wr,        *(const f32x4*)(wr + 4));
        bw[n][1] = cvt8(*(const f32x4*)(wr + 32), *(const f32x4*)(wr + 36));
    }
    const f32x4 oe0q = *(const f32x4*)(order_emb + dq);
    const f32x4 oe1q = *(const f32x4*)(order_emb + CD + dq);
    __syncthreads();   // s_emb / s_pi ready (once)

    // ---- iter-0 prefetch: eig rows + token rows ----
    f32x4 q00, q01, q10, q11;
    {
        const int2 ia = s_pi[dl];
        const float* e0 = eig_b + (size_t)ia.x * CK + koff;
        const float* e1 = eig_b + (size_t)ia.y * CK + koff;
        q00 = *(const f32x4*)e0; q01 = *(const f32x4*)(e0 + 4);
        q10 = *(const f32x4*)e1; q11 = *(const f32x4*)(e1 + 4);
    }
    i32x4 tokc[4];
#pragma unroll
    for (int s = 0; s < 4; ++s)
        tokc[s] = *(const i32x4*)(dptr + (size_t)(4 * s + wid) * CD + dq);

    for (int it = 0; it < TOK / 16; ++it) {
        const int t0 = it * 16;

        // s_emb gather for THIS iter's tokens (pre-barrier; overlaps MFMA)
        float embv[4][4];
#pragma unroll
        for (int s = 0; s < 4; ++s)
#pragma unroll
            for (int j = 0; j < 4; ++j)
                embv[s][j] = s_emb[tokc[s][j]];

        const bf16x8 a0 = cvt8(q00, q01);
        const bf16x8 a1 = cvt8(q10, q11);

        // prefetch NEXT iter's eig + token rows (allocating loads: L3 retains)
        i32x4 tokn[4];
        if (it + 1 < TOK / 16) {
            const int2 ia = s_pi[t0 + 16 + dl];
            const float* e0 = eig_b + (size_t)ia.x * CK + koff;
            const float* e1 = eig_b + (size_t)ia.y * CK + koff;
            q00 = *(const f32x4*)e0; q01 = *(const f32x4*)(e0 + 4);
            q10 = *(const f32x4*)e1; q11 = *(const f32x4*)(e1 + 4);
#pragma unroll
            for (int s = 0; s < 4; ++s)
                tokn[s] = *(const i32x4*)(dptr + (size_t)(t0 + 16 + 4 * s + wid) * CD + dq);
        }

        f32x4 acc[4];
#pragma unroll
        for (int n = 0; n < 4; ++n) {
            f32x4 z = {0.f, 0.f, 0.f, 0.f};
            z = __builtin_amdgcn_mfma_f32_16x16x32_bf16(a0, bw[n][0], z, 0, 0, 0);
            acc[n] = __builtin_amdgcn_mfma_f32_16x16x32_bf16(a1, bw[n][1], z, 0, 0, 0);
        }

        // transpose through LDS buf it&1 (iter it+2 writes can't pass barrier it+1)
#pragma unroll
        for (int n = 0; n < 4; ++n)
#pragma unroll
            for (int r = 0; r < 4; ++r)
                s_acc[it & 1][(lane >> 4) * 4 + r][wid * 64 + 16 * n + dl] = acc[n][r];
        asm volatile("s_waitcnt lgkmcnt(0)" ::: "memory");
        __builtin_amdgcn_s_barrier();

        // ---- minimal post-barrier epilogue: wave owns 4 rows, lane owns 4 d ----
#pragma unroll
        for (int s = 0; s < 4; ++s) {
            const int tr = 4 * s + wid;
            const int2 i01 = s_pi[t0 + tr];
            const f32x4 av = *(const f32x4*)&s_acc[it & 1][tr][4 * lane];
            const f32x4 oe = (i01.x == i01.y) ? oe1q : oe0q;
            f32x4 y;
            y[0] = av[0] + embv[s][0] + oe[0];
            y[1] = av[1] + embv[s][1] + oe[1];
            y[2] = av[2] + embv[s][2] + oe[2];
            y[3] = av[3] + embv[s][3] + oe[3];
            __builtin_nontemporal_store(
                y, (f32x4*)(outp + (size_t)(t0 + tr) * CD + dq));
        }

#pragma unroll
        for (int s = 0; s < 4; ++s) tokc[s] = tokn[s];
    }
}

extern "C" void kernel_launch(void* const* d_in, const int* in_sizes, int n_in,
                              void* d_out, int out_size, void* d_ws, size_t ws_size,
                              hipStream_t stream) {
    // inputs: 0 edge_index, 1 edge_data, 2 node_data, 3 node_num, 4 edge_num,
    // 5 padded_index, 6 padding_mask, 7 padded_node_mask, 8 padded_edge_mask,
    // 9 lap_eigvec, 10 emb_table, 11 lap_w, 12 order_emb
    const int*   edge_data    = (const int*)d_in[1];
    const int*   node_data    = (const int*)d_in[2];
    const int*   padded_index = (const int*)d_in[5];
    const float* lap_eigvec   = (const float*)d_in[9];
    const float* emb_table    = (const float*)d_in[10];
    const float* lap_w        = (const float*)d_in[11];
    const float* order_emb    = (const float*)d_in[12];
    float* out = (float*)d_out;

    dim3 grid(NBLK);  // 2304
    gft_mfma<<<grid, TPB, 0, stream>>>(node_data, edge_data, padded_index,
                                       lap_eigvec, emb_table, lap_w, order_emb, out);
}